// Round 1
// baseline (583.470 us; speedup 1.0000x reference)
//
#include <hip/hip_runtime.h>
#include <stdint.h>
#include <stddef.h>

// ---------------------------------------------------------------------------
// Neural SDE: B=2048 paths, 64 Euler-Maruyama steps.
// Strategy: batch-split persistent kernel. 128 WGs x 512 threads (8 waves),
// each WG owns 16 batch rows for all 64 steps (no inter-WG communication).
// Small weights live in LDS (bf16, MFMA-fragment-swizzled). Wc2 (128x2048,
// 512KB bf16) streams from L2 each step directly into MFMA B-fragments.
// ---------------------------------------------------------------------------

typedef __attribute__((ext_vector_type(8))) short bf16x8;   // 8 x bf16 (4 VGPR)
typedef __attribute__((ext_vector_type(4))) float f32x4;    // MFMA C/D
typedef __attribute__((ext_vector_type(4))) int   i32x4;    // 16B copies

// ---- ws layout (bytes), all bf16 fragment-swizzled weights --------------
#define WS_WI0 0        // 8 frags   (128x32  K=32  KI=1 NT=8)
#define WS_WI1 8192     // 32 frags  (128x128)
#define WS_WI2 40960    // 16 frags  (64x128)
#define WS_WV0 57344    // 16 frags  (128x64, t-col dropped)
#define WS_WV1 73728    // 32 frags
#define WS_WV2 106496   // 16 frags
#define WS_WC0 122880   // 16 frags
#define WS_WC1 139264   // 32 frags
#define WS_WC2 172032   // 512 frags (2048x128) = 512 KB
#define WS_TV0 696320   // Wv0[:,0] f32 [128]
#define WS_TC0 696832   // Wc0[:,0] f32 [128]
#define WS_END 697344

// ---- LDS layout (bytes) --------------------------------------------------
#define LD_WV0 0
#define LD_WV1 16384
#define LD_WV2 49152
#define LD_WC0 65536
#define LD_WC1 81920
#define LD_YBF 114688   // y as bf16 A-frags, K=64 (2048 B)
#define LD_H1V 116736   // K=128 act buffers (4096 B each)
#define LD_H1C 120832
#define LD_H2V 124928
#define LD_H2C 129024
#define LD_Y   133120   // f32 [16][65]
#define LD_DB  137280   // drift buf f32 [16][65]
#define LD_BM  141440   // f32 [16][33]
#define LD_BC2 143552   // bf16 [2048]
#define LD_SCC 147648   // bf16 [2048] (scale_c flat, index == col)
#define LD_BEV 151744   // f32 [128] eff bias v (t folded)
#define LD_BEC 152256
#define LD_BV1 152768
#define LD_BC1 153280
#define LD_BV2 153792
#define LD_SV  154048
#define LD_WR  154304   // f32 [8][65]
#define LD_BR  156384   // f32 [8]
#define LDS_TOTAL 156416

__device__ __forceinline__ short f2bf(float f) {
  uint32_t u = __builtin_bit_cast(uint32_t, f);
  uint32_t r = (u + 0x7fffu + ((u >> 16) & 1u)) >> 16;   // RNE
  return (short)r;
}
__device__ __forceinline__ float bf2f(short s) {
  uint32_t u = ((uint32_t)(uint16_t)s) << 16;
  return __builtin_bit_cast(float, u);
}
__device__ __forceinline__ float tanh_fast(float x) {
  x = fminf(15.f, fmaxf(-15.f, x));
  float e = __builtin_amdgcn_exp2f(x * 2.8853900817779268f); // 2*log2(e)
  return (e - 1.f) * __builtin_amdgcn_rcpf(e + 1.f);
}
__device__ __forceinline__ float lipswish(float x) {
  float s = __builtin_amdgcn_rcpf(1.f + __builtin_amdgcn_exp2f(-1.4426950408889634f * x));
  return 0.909f * x * s;
}
// sum over the 16 lanes of each DPP row (our n-dimension); result in all lanes
__device__ __forceinline__ float red16(float x) {
  int v;
  v = __builtin_amdgcn_update_dpp(0, __builtin_bit_cast(int, x), 0xB1, 0xF, 0xF, true); // quad xor1
  x += __builtin_bit_cast(float, v);
  v = __builtin_amdgcn_update_dpp(0, __builtin_bit_cast(int, x), 0x4E, 0xF, 0xF, true); // quad xor2
  x += __builtin_bit_cast(float, v);
  v = __builtin_amdgcn_update_dpp(0, __builtin_bit_cast(int, x), 0x141, 0xF, 0xF, true); // row_half_mirror (^4 on quad-uniform)
  x += __builtin_bit_cast(float, v);
  v = __builtin_amdgcn_update_dpp(0, __builtin_bit_cast(int, x), 0x140, 0xF, 0xF, true); // row_mirror (^8)
  x += __builtin_bit_cast(float, v);
  return x;
}
// write activation element (m,k) into a fragment-swizzled bf16 A-buffer
__device__ __forceinline__ void write_act(char* buf, int m, int k, short v) {
  int addr = ((k >> 5) << 10) + (m + ((k >> 3) & 3) * 16) * 16 + ((k & 7) << 1);
  *(short*)(buf + addr) = v;
}

template<int KF>
__device__ __forceinline__ f32x4 gemm_tile(const char* abase, const char* bbase, int lane) {
  f32x4 acc = {0.f, 0.f, 0.f, 0.f};
#pragma unroll
  for (int k = 0; k < KF; k++) {
    bf16x8 a = *(const bf16x8*)(abase + k * 1024 + lane * 16);
    bf16x8 b = *(const bf16x8*)(bbase + k * 1024 + lane * 16);
    acc = __builtin_amdgcn_mfma_f32_16x16x32_bf16(a, b, acc, 0, 0, 0);
  }
  return acc;
}

// ---------------------------------------------------------------------------
// Prep: convert f32 weights -> bf16 fragment-swizzled blobs in ws.
// frag layout: for W[N][K]: frag(nt,ki) holds B[k][n] for n=nt*16+(lane&15),
// k=ki*32+(lane>>4)*8+j  at ws_off + frag*1024 + lane*16 + j*2.
// ---------------------------------------------------------------------------
__global__ __launch_bounds__(256) void prep_kernel(
    const float* Wi0, const float* Wi1, const float* Wi2,
    const float* Wv0, const float* Wv1, const float* Wv2,
    const float* Wc0, const float* Wc1, const float* Wc2, char* ws) {
  int gid = blockIdx.x * 256 + threadIdx.x;
  if (gid < 680 * 64) {
    int frag = gid >> 6, lane = gid & 63;
    const float* src; int start, KI, srcK, c0;
    if      (frag < 8)   { src = Wi0; start = 0;   KI = 1; srcK = 32;  c0 = 0; }
    else if (frag < 40)  { src = Wi1; start = 8;   KI = 4; srcK = 128; c0 = 0; }
    else if (frag < 56)  { src = Wi2; start = 40;  KI = 4; srcK = 128; c0 = 0; }
    else if (frag < 72)  { src = Wv0; start = 56;  KI = 2; srcK = 65;  c0 = 1; }
    else if (frag < 104) { src = Wv1; start = 72;  KI = 4; srcK = 128; c0 = 0; }
    else if (frag < 120) { src = Wv2; start = 104; KI = 4; srcK = 128; c0 = 0; }
    else if (frag < 136) { src = Wc0; start = 120; KI = 2; srcK = 65;  c0 = 1; }
    else if (frag < 168) { src = Wc1; start = 136; KI = 4; srcK = 128; c0 = 0; }
    else                 { src = Wc2; start = 168; KI = 4; srcK = 128; c0 = 0; }
    int rel = frag - start;
    int nt = rel / KI, ki = rel % KI;
    int n16 = lane & 15, quad = lane >> 4;
    const float* s = src + (nt * 16 + n16) * srcK + c0 + ki * 32 + quad * 8;
    bf16x8 v;
#pragma unroll
    for (int j = 0; j < 8; j++) v[j] = f2bf(s[j]);
    *(bf16x8*)(ws + (size_t)frag * 1024 + lane * 16) = v;
  } else {
    int i = gid - 680 * 64;
    if (i < 128)      ((float*)(ws + WS_TV0))[i] = Wv0[i * 65];
    else if (i < 256) ((float*)(ws + WS_TC0))[i - 128] = Wc0[(i - 128) * 65];
  }
}

// ---------------------------------------------------------------------------
// Main persistent kernel: one WG = 16 batch rows, all 64 steps.
// ---------------------------------------------------------------------------
__global__ __launch_bounds__(512, 2) void sde_kernel(
    const float* ts, const float* init_noise, const float* bm,
    const float* bi0, const float* bi1, const float* bi2,
    const float* bv0, const float* bv1, const float* bv2, const float* scale_v,
    const float* bc0, const float* bc1, const float* bc2, const float* scale_c,
    const float* Wr, const float* br,
    const char* ws, float* out) {
  extern __shared__ __align__(16) char lds[];
  const int tid  = threadIdx.x;
  const int lane = tid & 63;
  const int wv   = tid >> 6;     // wave 0..7
  const int nl   = lane & 15;
  const int quad = lane >> 4;
  const int b0   = blockIdx.x * 16;

  // ---- stage persistent weights & params into LDS ----
  {
    const i32x4* s = (const i32x4*)(ws + WS_WV0);   // Wv0b..Wc1b contiguous 114688 B
    i32x4* d = (i32x4*)lds;
    for (int j = tid; j < 7168; j += 512) d[j] = s[j];
  }
  for (int j = tid; j < 2048; j += 512) {
    ((short*)(lds + LD_BC2))[j] = f2bf(bc2[j]);
    ((short*)(lds + LD_SCC))[j] = f2bf(scale_c[j]);
  }
  if (tid < 128)      { ((float*)(lds + LD_BV1))[tid] = bv1[tid];
                        ((float*)(lds + LD_BC1))[tid] = bc1[tid]; }
  else if (tid < 192) { int k = tid - 128; ((float*)(lds + LD_BV2))[k] = bv2[k];
                        ((float*)(lds + LD_SV))[k] = scale_v[k]; }
  else if (tid < 200) { int k = tid - 192; ((float*)(lds + LD_BR))[k] = br[k]; }
  { int dd = tid >> 6, k = tid & 63;
    ((float*)(lds + LD_WR))[dd * 65 + k] = Wr[tid >> 6 ? dd * 64 + k : k];  }
  __syncthreads();

  // fix Wr staging cleanly (overwrite; cheap)
  { int dd = tid >> 6, k = tid & 63;
    ((float*)(lds + LD_WR))[dd * 65 + k] = Wr[dd * 64 + k]; }
  __syncthreads();

  // ---- init MLP: noise -> y0 ----
  { int m = tid >> 5, k = tid & 31;
    write_act(lds + LD_YBF, m, k, f2bf(init_noise[(b0 + m) * 32 + k])); }
  __syncthreads();
  { // L1i (relu), 8 tiles
    f32x4 acc = gemm_tile<1>(lds + LD_YBF, ws + WS_WI0 + wv * 1024, lane);
    int col = wv * 16 + nl; float bias = bi0[col];
#pragma unroll
    for (int r = 0; r < 4; r++)
      write_act(lds + LD_H1V, quad * 4 + r, col, f2bf(fmaxf(0.f, acc[r] + bias)));
  }
  __syncthreads();
  { // L2i (relu)
    f32x4 acc = gemm_tile<4>(lds + LD_H1V, ws + WS_WI1 + wv * 4096, lane);
    int col = wv * 16 + nl; float bias = bi1[col];
#pragma unroll
    for (int r = 0; r < 4; r++)
      write_act(lds + LD_H2V, quad * 4 + r, col, f2bf(fmaxf(0.f, acc[r] + bias)));
  }
  __syncthreads();
  if (wv < 4) { // L3i (identity) -> y f32
    f32x4 acc = gemm_tile<4>(lds + LD_H2V, ws + WS_WI2 + wv * 4096, lane);
    int col = wv * 16 + nl; float bias = bi2[col];
#pragma unroll
    for (int r = 0; r < 4; r++)
      ((float*)(lds + LD_Y))[(quad * 4 + r) * 65 + col] = acc[r] + bias;
  }
  __syncthreads();

  // ---- M0: ybf from y; bm step0; effective biases step0 ----
  const float ts0 = ts[0];
  for (int e = tid; e < 1024; e += 512) {
    int row = e >> 6, k = e & 63;
    write_act(lds + LD_YBF, row, k, f2bf(((float*)(lds + LD_Y))[row * 65 + k]));
  }
  { int row = tid >> 5, n = tid & 31;
    ((float*)(lds + LD_BM))[row * 33 + n] = bm[((size_t)(b0 + row) * 64 + 0) * 32 + n]; }
  if (tid < 128)
    ((float*)(lds + LD_BEV))[tid] = bv0[tid] + ts0 * ((const float*)(ws + WS_TV0))[tid];
  else if (tid < 256) { int k = tid - 128;
    ((float*)(lds + LD_BEC))[k] = bc0[k] + ts0 * ((const float*)(ws + WS_TC0))[k]; }
  __syncthreads();

  // ================= 64-step scan =================
  for (int step = 0; step < 64; step++) {
    // ---- Phase A: layer 1 (v and c) ----
    {
      int col = wv * 16 + nl;
      {
        f32x4 acc = gemm_tile<2>(lds + LD_YBF, lds + LD_WV0 + wv * 2048, lane);
        float bias = ((float*)(lds + LD_BEV))[col];
#pragma unroll
        for (int r = 0; r < 4; r++)
          write_act(lds + LD_H1V, quad * 4 + r, col, f2bf(lipswish(acc[r] + bias)));
      }
      {
        f32x4 acc = gemm_tile<2>(lds + LD_YBF, lds + LD_WC0 + wv * 2048, lane);
        float bias = ((float*)(lds + LD_BEC))[col];
#pragma unroll
        for (int r = 0; r < 4; r++)
          write_act(lds + LD_H1C, quad * 4 + r, col, f2bf(lipswish(acc[r] + bias)));
      }
    }
    __syncthreads();
    // ---- Layer 2 ----
    {
      int col = wv * 16 + nl;
      {
        f32x4 acc = gemm_tile<4>(lds + LD_H1V, lds + LD_WV1 + wv * 4096, lane);
        float bias = ((float*)(lds + LD_BV1))[col];
#pragma unroll
        for (int r = 0; r < 4; r++)
          write_act(lds + LD_H2V, quad * 4 + r, col, f2bf(lipswish(acc[r] + bias)));
      }
      {
        f32x4 acc = gemm_tile<4>(lds + LD_H1C, lds + LD_WC1 + wv * 4096, lane);
        float bias = ((float*)(lds + LD_BC1))[col];
#pragma unroll
        for (int r = 0; r < 4; r++)
          write_act(lds + LD_H2C, quad * 4 + r, col, f2bf(lipswish(acc[r] + bias)));
      }
    }
    __syncthreads();
    // ---- Layer 3: drift (waves 0-3) + controlled field (all waves) ----
    if (wv < 4) {
      f32x4 acc = gemm_tile<4>(lds + LD_H2V, lds + LD_WV2 + wv * 4096, lane);
      int col = wv * 16 + nl;
      float bias = ((float*)(lds + LD_BV2))[col];
      float sv   = ((float*)(lds + LD_SV))[col];
#pragma unroll
      for (int r = 0; r < 4; r++)
        ((float*)(lds + LD_DB))[(quad * 4 + r) * 65 + col] = sv * tanh_fast(acc[r] + bias);
    }
    {
      bf16x8 a[4];
#pragma unroll
      for (int k = 0; k < 4; k++)
        a[k] = *(const bf16x8*)(lds + LD_H2C + k * 1024 + lane * 16);
      float bmr0[4], bmr1[4];
#pragma unroll
      for (int r = 0; r < 4; r++) {
        bmr0[r] = ((float*)(lds + LD_BM))[(quad * 4 + r) * 33 + nl];
        bmr1[r] = ((float*)(lds + LD_BM))[(quad * 4 + r) * 33 + 16 + nl];
      }
      const char* wc2 = ws + WS_WC2 + (size_t)(wv * 16) * 4096;
      bf16x8 bcur[4], bnxt[4];
#pragma unroll
      for (int k = 0; k < 4; k++)
        bcur[k] = *(const bf16x8*)(wc2 + k * 1024 + lane * 16);
      float ps[4] = {0.f, 0.f, 0.f, 0.f};
#pragma unroll
      for (int tt = 0; tt < 16; tt++) {
        if (tt < 15) {
#pragma unroll
          for (int k = 0; k < 4; k++)
            bnxt[k] = *(const bf16x8*)(wc2 + (tt + 1) * 4096 + k * 1024 + lane * 16);
        }
        f32x4 acc = {0.f, 0.f, 0.f, 0.f};
#pragma unroll
        for (int k = 0; k < 4; k++)
          acc = __builtin_amdgcn_mfma_f32_16x16x32_bf16(a[k], bcur[k], acc, 0, 0, 0);
        int ntA = wv * 16 + tt;
        int col = ntA * 16 + nl;                 // == h*32+n
        float bc2v = bf2f(((short*)(lds + LD_BC2))[col]);
        float scv  = bf2f(((short*)(lds + LD_SCC))[col]);
        int half = tt & 1;
#pragma unroll
        for (int r = 0; r < 4; r++) {
          float bmv = half ? bmr1[r] : bmr0[r];
          float p = tanh_fast(acc[r] + bc2v) * scv * bmv;
          ps[r] = half ? (ps[r] + p) : p;
        }
        if (half) {  // finished an h (pair of 16-col tiles): reduce over 32 n's
#pragma unroll
          for (int r = 0; r < 4; r++) ps[r] = red16(ps[r]);
          if (nl < 4) {
            int row = quad * 4 + nl;
            float s = (nl == 0) ? ps[0] : (nl == 1) ? ps[1] : (nl == 2) ? ps[2] : ps[3];
            float* yp = (float*)(lds + LD_Y) + row * 65 + (ntA >> 1);
            *yp += s;   // exclusive h-range per wave: race-free
          }
        }
#pragma unroll
        for (int k = 0; k < 4; k++) bcur[k] = bnxt[k];
      }
    }
    __syncthreads();
    // ---- M: y += drift; build ybf; stage next bm & effective biases ----
    for (int e = tid; e < 1024; e += 512) {
      int row = e >> 6, k = e & 63;
      float* yp = (float*)(lds + LD_Y) + row * 65 + k;
      float v = *yp + ((float*)(lds + LD_DB))[row * 65 + k];
      *yp = v;
      write_act(lds + LD_YBF, row, k, f2bf(v));
    }
    if (step + 1 < 64) {
      int row = tid >> 5, n = tid & 31;
      ((float*)(lds + LD_BM))[row * 33 + n] =
          bm[((size_t)(b0 + row) * 64 + (step + 1)) * 32 + n];
      float tnext = ts0 + (float)(step + 1);
      if (tid < 128)
        ((float*)(lds + LD_BEV))[tid] = bv0[tid] + tnext * ((const float*)(ws + WS_TV0))[tid];
      else if (tid < 256) { int k = tid - 128;
        ((float*)(lds + LD_BEC))[k] = bc0[k] + tnext * ((const float*)(ws + WS_TC0))[k]; }
    }
    __syncthreads();
    // ---- R: readout (overlaps next step's phase A in waves 2-7) ----
    if (tid < 128) {
      int row = tid >> 3, dd = tid & 7;
      const float* yr = (const float*)(lds + LD_Y) + row * 65;
      const float* wr = (const float*)(lds + LD_WR) + dd * 65;
      float s = ((float*)(lds + LD_BR))[dd];
#pragma unroll
      for (int k = 0; k < 64; k++) s = fmaf(yr[k], wr[k], s);
      out[(size_t)(b0 + row) * 512 + step * 8 + dd] = s;
    }
  }
}

extern "C" void kernel_launch(void* const* d_in, const int* in_sizes, int n_in,
                              void* d_out, int out_size, void* d_ws, size_t ws_size,
                              hipStream_t stream) {
  (void)in_sizes; (void)n_in; (void)out_size; (void)ws_size;
  const float* ts         = (const float*)d_in[0];
  const float* init_noise = (const float*)d_in[1];
  const float* bm         = (const float*)d_in[2];
  const float* Wi0 = (const float*)d_in[3];
  const float* bi0 = (const float*)d_in[4];
  const float* Wi1 = (const float*)d_in[5];
  const float* bi1 = (const float*)d_in[6];
  const float* Wi2 = (const float*)d_in[7];
  const float* bi2 = (const float*)d_in[8];
  const float* scale_v = (const float*)d_in[9];
  const float* Wv0 = (const float*)d_in[10];
  const float* bv0 = (const float*)d_in[11];
  const float* Wv1 = (const float*)d_in[12];
  const float* bv1 = (const float*)d_in[13];
  const float* Wv2 = (const float*)d_in[14];
  const float* bv2 = (const float*)d_in[15];
  const float* scale_c = (const float*)d_in[16];
  const float* Wc0 = (const float*)d_in[17];
  const float* bc0 = (const float*)d_in[18];
  const float* Wc1 = (const float*)d_in[19];
  const float* bc1 = (const float*)d_in[20];
  const float* Wc2 = (const float*)d_in[21];
  const float* bc2 = (const float*)d_in[22];
  const float* Wr  = (const float*)d_in[23];
  const float* br  = (const float*)d_in[24];
  char*  ws  = (char*)d_ws;
  float* out = (float*)d_out;

  hipFuncSetAttribute((const void*)sde_kernel,
                      hipFuncAttributeMaxDynamicSharedMemorySize, LDS_TOTAL);

  prep_kernel<<<171, 256, 0, stream>>>(Wi0, Wi1, Wi2, Wv0, Wv1, Wv2, Wc0, Wc1, Wc2, ws);
  sde_kernel<<<128, 512, LDS_TOTAL, stream>>>(
      ts, init_noise, bm, bi0, bi1, bi2, bv0, bv1, bv2, scale_v,
      bc0, bc1, bc2, scale_c, Wr, br, ws, out);
}